// Round 16
// baseline (945.079 us; speedup 1.0000x reference)
//
#include <hip/hip_runtime.h>
#include <stdint.h>

typedef unsigned int u32;
typedef __bf16 bf16_t;
typedef bf16_t bf16x8 __attribute__((ext_vector_type(8)));
typedef bf16_t bf16x4 __attribute__((ext_vector_type(4)));
typedef float  f32x4  __attribute__((ext_vector_type(4)));

#define NB   256
#define NN   196
#define CD   2048
#define QD   1024
#define NE   1024
#define NG   8

// workspace layout (bytes) — ~6.8 MB
#define WS_QP    0
#define WS_ATTN  (NB*NE*4)                              // 1,048,576
#define WS_WCB   (WS_ATTN + NB*NG*NN*4)                 // 2,654,208

__device__ __forceinline__ bf16_t f2bf(float f){
  u32 u = __float_as_uint(f);
  u += 0x7fffu + ((u >> 16) & 1u);            // RNE
  unsigned short h = (unsigned short)(u >> 16);
  return __builtin_bit_cast(bf16_t, h);
}

__device__ __forceinline__ float fast_tanh(float x){
  float e = __expf(2.0f * x);
  return 1.0f - 2.0f / (e + 1.0f);
}

__device__ __forceinline__ void load_lds16(const void* g, void* l){
  __builtin_amdgcn_global_load_lds(
      (const __attribute__((address_space(1))) void*)g,
      (__attribute__((address_space(3))) void*)l, 16, 0, 0);
}

// ---------------- Wc f32 -> bf16 ----------------
__global__ __launch_bounds__(256)
void k_conv(const float* __restrict__ src, bf16_t* __restrict__ dst){
  size_t i = ((size_t)blockIdx.x * 256 + threadIdx.x) * 4;
  float4 v = *(const float4*)(src + i);
  bf16x4 o = { f2bf(v.x), f2bf(v.y), f2bf(v.z), f2bf(v.w) };
  *(bf16x4*)(dst + i) = o;
}

// ---------------- qp = query @ Wq^T + bq  (f32, 32x32 tiles) ----------------
__global__ __launch_bounds__(256)
void k_qp(const float* __restrict__ query, const float* __restrict__ Wq,
          const float* __restrict__ bq, float* __restrict__ qp){
  __shared__ float qs[32][36];
  __shared__ float wsm[32][36];
  const u32 t  = threadIdx.x;
  const u32 e0 = blockIdx.x * 32, b0 = blockIdx.y * 32;
  const u32 r  = t >> 3, ci = (t & 7) * 4;
  const u32 tm = (t >> 4) * 2, tn = (t & 15) * 2;
  float c00 = 0.f, c01 = 0.f, c10 = 0.f, c11 = 0.f;
  for (u32 k0 = 0; k0 < QD; k0 += 32){
    float4 qv = *(const float4*)(query + (size_t)(b0 + r) * QD + k0 + ci);
    float4 wv = *(const float4*)(Wq    + (size_t)(e0 + r) * QD + k0 + ci);
    __syncthreads();
    *(float4*)&qs[r][ci]  = qv;
    *(float4*)&wsm[r][ci] = wv;
    __syncthreads();
    #pragma unroll
    for (int kq = 0; kq < 8; kq++){
      float4 a0 = *(const float4*)&qs[tm][kq*4];
      float4 a1 = *(const float4*)&qs[tm+1][kq*4];
      float4 b0v = *(const float4*)&wsm[tn][kq*4];
      float4 b1v = *(const float4*)&wsm[tn+1][kq*4];
      c00 += a0.x*b0v.x + a0.y*b0v.y + a0.z*b0v.z + a0.w*b0v.w;
      c01 += a0.x*b1v.x + a0.y*b1v.y + a0.z*b1v.z + a0.w*b1v.w;
      c10 += a1.x*b0v.x + a1.y*b0v.y + a1.z*b0v.z + a1.w*b0v.w;
      c11 += a1.x*b1v.x + a1.y*b1v.y + a1.z*b1v.z + a1.w*b1v.w;
    }
  }
  float bq0 = bq[e0+tn], bq1 = bq[e0+tn+1];
  qp[(size_t)(b0+tm  )*NE + e0+tn  ] = c00 + bq0;
  qp[(size_t)(b0+tm  )*NE + e0+tn+1] = c01 + bq1;
  qp[(size_t)(b0+tm+1)*NE + e0+tn  ] = c10 + bq0;
  qp[(size_t)(b0+tm+1)*NE + e0+tn+1] = c11 + bq1;
}

#define BM 128
#define BN 128
#define BK 32
#define KSTEPS (CD/BK)   // 64

// ===== main: A = f32 ctx fragments DIRECT global->reg (1-step prefetch, =====
// ===== cvt in-register); B = bf16 wcb via global_load_lds 2-buffer.     =====
// LDS K-loop: B bufs @0,8192 (128 rows x 64B bf16, 4-slot XOR swz) — A not in LDS.
// epilogue overlay: comb[128][136]bf16 @0; qp0 @34816; qp1 @35328; bc @35840
__global__ __launch_bounds__(256, 3)
void k_mainB(const float* __restrict__ ctx, const bf16_t* __restrict__ wcb,
             const float* __restrict__ qp, const float* __restrict__ bcv,
             const float* __restrict__ Wo, float* __restrict__ attn)
{
  __shared__ char smem[36864] __attribute__((aligned(128)));

  const u32 tid  = threadIdx.x;
  const u32 lane = tid & 63;
  const u32 wave = tid >> 6;
  const u32 wm   = wave >> 1;
  const u32 wn   = wave & 1;

  // XCD swizzle: 8 e-chunks of one m-stripe land on one XCD (grid 3136 = 8*392)
  u32 d  = blockIdx.x;
  u32 x  = d & 7;
  u32 s  = d >> 3;
  u32 ec = s & 7;
  u32 j  = s >> 3;
  u32 ms = j * 8 + x;                 // 0..391
  const u32 m0 = ms * BM;
  const u32 e0 = ec * BN;

  const u32 q   = lane >> 4;
  const u32 r15 = lane & 15;

  // ---- A: per-lane direct fragment source. lane covers row wm*64+mt*16+r15,
  //      cols [q*8, q*8+8) f32 of the current K-slice.
  const float* aBase = ctx + (size_t)(m0 + wm*64 + r15) * CD + q * 8;

  // ---- B staging (bf16): row = tid>>2, phys slot = tid&3, quarter = slot^((row>>1)&3)
  const u32 brow0 = tid >> 2;
  const u32 brow1 = (tid + 256) >> 2;
  const u32 bkq0  = (tid & 3) ^ ((tid >> 3) & 3);
  const u32 bkq1  = (tid & 3) ^ (((tid + 256) >> 3) & 3);
  const bf16_t* bS0 = wcb + (size_t)(e0 + brow0) * CD + bkq0 * 8;
  const bf16_t* bS1 = wcb + (size_t)(e0 + brow1) * CD + bkq1 * 8;
  char* bD0 = smem + tid * 16;
  char* bD1 = bD0 + 4096;

  f32x4 acc[4][4];
  #pragma unroll
  for (int i = 0; i < 4; i++)
    #pragma unroll
    for (int jn = 0; jn < 4; jn++) acc[i][jn] = (f32x4){0.f,0.f,0.f,0.f};

  auto stageB = [&](u32 buf, u32 ks){
    const u32 ko = ks * BK;
    load_lds16(bS0 + ko, bD0 + buf * 8192u);
    load_lds16(bS1 + ko, bD1 + buf * 8192u);
  };

  // B read swizzle: slot q ^ ((r15>>1)&3) of a 64B row
  const u32 bsw = (q ^ ((r15 >> 1) & 3)) * 16;

  f32x4 avA[4][2], avB[4][2];

#define PREF_A(DST, KS) do{                                                     \
    const float* p_ = aBase + (size_t)(KS) * BK;                                \
    _Pragma("unroll")                                                           \
    for (int mt = 0; mt < 4; mt++){                                             \
      DST[mt][0] = *(const f32x4*)(p_ + (size_t)mt * 16 * CD);                  \
      DST[mt][1] = *(const f32x4*)(p_ + (size_t)mt * 16 * CD + 4);              \
    }                                                                           \
  }while(0)

#define COMPUTE(BUF, SRC) do{                                                   \
    const char* B_ = smem + (BUF) * 8192u;                                      \
    bf16x8 af[4], bfr[4];                                                       \
    _Pragma("unroll")                                                           \
    for (int mt = 0; mt < 4; mt++){                                             \
      af[mt] = (bf16x8){ (bf16_t)SRC[mt][0][0], (bf16_t)SRC[mt][0][1],          \
                         (bf16_t)SRC[mt][0][2], (bf16_t)SRC[mt][0][3],          \
                         (bf16_t)SRC[mt][1][0], (bf16_t)SRC[mt][1][1],          \
                         (bf16_t)SRC[mt][1][2], (bf16_t)SRC[mt][1][3] };        \
    }                                                                           \
    _Pragma("unroll")                                                           \
    for (int nt = 0; nt < 4; nt++){                                             \
      u32 row_ = wn*64 + nt*16 + r15;                                           \
      bfr[nt] = *(const bf16x8*)(B_ + row_*64 + bsw);                           \
    }                                                                           \
    _Pragma("unroll")                                                           \
    for (int mt = 0; mt < 4; mt++)                                              \
      _Pragma("unroll")                                                         \
      for (int nt = 0; nt < 4; nt++)                                            \
        acc[mt][nt] = __builtin_amdgcn_mfma_f32_16x16x32_bf16(                  \
            af[mt], bfr[nt], acc[mt][nt], 0, 0, 0);                             \
  }while(0)

  // prologue
  PREF_A(avA, 0);
  stageB(0, 0);
  __syncthreads();

  // unrolled by 2 for static register-buffer indices (KSTEPS = 64, even)
  for (u32 ks = 0; ks < KSTEPS; ks += 2){
    stageB((ks + 1) & 1, ks + 1);            // ks+1 <= 63 always valid
    PREF_A(avB, ks + 1);
    COMPUTE(ks & 1, avA);
    __syncthreads();
    if (ks + 2 < KSTEPS){
      stageB((ks + 2) & 1, ks + 2);
      PREF_A(avA, ks + 2);
    }
    COMPUTE((ks + 1) & 1, avB);
    __syncthreads();
  }

  // ---------------- epilogue ----------------
  float*  qp0  = (float*)(smem + 34816);
  float*  qp1  = (float*)(smem + 35328);
  float*  bcs  = (float*)(smem + 35840);
  bf16_t* comb = (bf16_t*)smem;                // [128][136]

  const u32 b0  = m0 / 196u;
  const u32 bnd = (b0 + 1) * 196u - m0;        // local rows >= bnd belong to b0+1

  if (tid < 128){
    qp0[tid] = qp[(size_t)b0 * NE + e0 + tid];
    bcs[tid] = bcv[e0 + tid];
  } else {
    u32 b1 = b0 + 1; if (b1 >= NB) b1 = NB - 1;
    qp1[tid - 128] = qp[(size_t)b1 * NE + e0 + (tid - 128)];
  }

  // Wo fragments (A operand of attn MFMA): row=g (lane&15), k=e
  bf16x8 wf[4];
  {
    u32 g = lane & 15;
    #pragma unroll
    for (int kk = 0; kk < 4; kk++){
      #pragma unroll
      for (int rr = 0; rr < 8; rr++){
        u32 ei = e0 + kk*32 + q*8 + rr;
        float v = (g < NG) ? Wo[(size_t)g * NE + ei] : 0.0f;
        wf[kk][rr] = f2bf(v);
      }
    }
  }
  __syncthreads();

  // tanh(cp + qp + bc) -> comb (bf16)
  #pragma unroll
  for (int nt = 0; nt < 4; nt++){
    u32 el = wn*64 + nt*16 + r15;
    float qa = qp0[el];
    float qb = qp1[el];
    float bcx = bcs[el];
    #pragma unroll
    for (int mt = 0; mt < 4; mt++){
      u32 rl = wm*64 + mt*16 + q*4;
      #pragma unroll
      for (int r = 0; r < 4; r++){
        u32 row = rl + r;
        float qv = (row >= bnd) ? qb : qa;
        float t = fast_tanh(acc[mt][nt][r] + qv + bcx);
        comb[row*136 + el] = f2bf(t);
      }
    }
  }
  __syncthreads();

  // attn_partial^T[g][n] = sum_e Wo[g,e]*comb[n,e] (two 16-row tiles per wave)
  #pragma unroll
  for (int i = 0; i < 2; i++){
    u32 nrow = (wave*2 + i)*16 + r15;
    f32x4 at = (f32x4){0.f,0.f,0.f,0.f};
    #pragma unroll
    for (int kk = 0; kk < 4; kk++){
      bf16x8 cf = *(const bf16x8*)&comb[nrow*136 + kk*32 + q*8];
      at = __builtin_amdgcn_mfma_f32_16x16x32_bf16(wf[kk], cf, at, 0, 0, 0);
    }
    if (q < 2){
      u32 mrow = m0 + nrow;
      u32 bb = mrow / 196u;
      u32 nn = mrow - bb * 196u;
      #pragma unroll
      for (int r = 0; r < 4; r++){
        u32 g = q*4 + r;
        atomicAdd(&attn[((size_t)bb * NG + g) * NN + nn], at[r]);
      }
    }
  }
}

// ---------------- softmax over n per (b,g) ----------------
__global__ __launch_bounds__(256)
void k_softmax(float* __restrict__ attn){
  u32 flat = blockIdx.x * 4 + (threadIdx.x >> 6);
  u32 lane = threadIdx.x & 63;
  float* row = attn + (size_t)flat * NN;
  float v0 = row[lane];
  float v1 = row[lane + 64];
  float v2 = row[lane + 128];
  float v3 = (lane < 4) ? row[lane + 192] : -1e30f;
  float m = fmaxf(fmaxf(v0, v1), fmaxf(v2, v3));
  #pragma unroll
  for (int o = 1; o < 64; o <<= 1) m = fmaxf(m, __shfl_xor(m, o));
  float e0 = __expf(v0 - m), e1 = __expf(v1 - m), e2 = __expf(v2 - m);
  float e3 = (lane < 4) ? __expf(v3 - m) : 0.f;
  float sum = e0 + e1 + e2 + e3;
  #pragma unroll
  for (int o = 1; o < 64; o <<= 1) sum += __shfl_xor(sum, o);
  float inv = 1.0f / sum;
  row[lane]       = e0 * inv;
  row[lane + 64]  = e1 * inv;
  row[lane + 128] = e2 * inv;
  if (lane < 4) row[lane + 192] = e3 * inv;
}

// -------- glimpse (f32 ctx — accuracy-critical; R4-proven config) --------
__global__ __launch_bounds__(256)
void k_glimpse(const float* __restrict__ ctx, const float* __restrict__ w,
               float* __restrict__ out){
  const u32 b  = blockIdx.y;
  const u32 c0 = blockIdx.x * 512 + threadIdx.x * 2;
  __shared__ float ws_[NG * NN];
  for (u32 i = threadIdx.x; i < NG * NN; i += 256)
    ws_[i] = w[(size_t)b * NG * NN + i];
  __syncthreads();
  const float* cp = ctx + (size_t)b * NN * CD + c0;
  float2 acc[NG];
  #pragma unroll
  for (int g = 0; g < NG; g++) acc[g] = make_float2(0.f, 0.f);
  for (u32 n = 0; n < NN; n++){
    float2 v = *(const float2*)(cp + (size_t)n * CD);
    #pragma unroll
    for (int g = 0; g < NG; g++){
      float wv = ws_[g * NN + n];
      acc[g].x = fmaf(wv, v.x, acc[g].x);
      acc[g].y = fmaf(wv, v.y, acc[g].y);
    }
  }
  #pragma unroll
  for (int g = 0; g < NG; g++)
    *(float2*)(out + (size_t)b * (NG * CD) + (size_t)g * CD + c0) = acc[g];
}

extern "C" void kernel_launch(void* const* d_in, const int* in_sizes, int n_in,
                              void* d_out, int out_size, void* d_ws, size_t ws_size,
                              hipStream_t stream)
{
  const float* ctx   = (const float*)d_in[0];
  const float* query = (const float*)d_in[1];
  const float* Wq    = (const float*)d_in[2];
  const float* bq    = (const float*)d_in[3];
  const float* Wc    = (const float*)d_in[4];
  const float* bc    = (const float*)d_in[5];
  const float* Wo    = (const float*)d_in[6];
  // d_in[7] = bo: constant over softmax axis -> cancels, unused.

  char* ws = (char*)d_ws;
  float*  qp   = (float*)(ws + WS_QP);
  float*  attn = (float*)(ws + WS_ATTN);
  bf16_t* wcb  = (bf16_t*)(ws + WS_WCB);
  float*  out  = (float*)d_out;

  (void)hipMemsetAsync(attn, 0, (size_t)NB * NG * NN * 4, stream);
  k_conv<<<2048, 256, 0, stream>>>(Wc, wcb);
  k_qp<<<dim3(32, 8), 256, 0, stream>>>(query, Wq, bq, qp);
  k_mainB<<<3136, 256, 0, stream>>>(ctx, wcb, qp, bc, Wo, attn);
  k_softmax<<<512, 256, 0, stream>>>(attn);
  k_glimpse<<<dim3(4, 256), 256, 0, stream>>>(ctx, attn, out);
}

// Round 17
// 480.818 us; speedup vs baseline: 1.9656x; 1.9656x over previous
//
#include <hip/hip_runtime.h>
#include <stdint.h>

typedef unsigned int u32;
typedef __bf16 bf16_t;
typedef bf16_t bf16x8 __attribute__((ext_vector_type(8)));
typedef bf16_t bf16x4 __attribute__((ext_vector_type(4)));
typedef float  f32x4  __attribute__((ext_vector_type(4)));

#define NB   256
#define NN   196
#define CD   2048
#define QD   1024
#define NE   1024
#define NG   8

// workspace layout (bytes) — no ctxb: total need ~6.8 MB
#define WS_QP    0
#define WS_ATTN  (NB*NE*4)                              // 1,048,576
#define WS_WCB   (WS_ATTN + NB*NG*NN*4)                 // 2,654,208

__device__ __forceinline__ bf16_t f2bf(float f){
  u32 u = __float_as_uint(f);
  u += 0x7fffu + ((u >> 16) & 1u);            // RNE
  unsigned short h = (unsigned short)(u >> 16);
  return __builtin_bit_cast(bf16_t, h);
}

__device__ __forceinline__ float fast_tanh(float x){
  float e = __expf(2.0f * x);
  return 1.0f - 2.0f / (e + 1.0f);
}

__device__ __forceinline__ void load_lds16(const void* g, void* l){
  __builtin_amdgcn_global_load_lds(
      (const __attribute__((address_space(1))) void*)g,
      (__attribute__((address_space(3))) void*)l, 16, 0, 0);
}

// ---------------- Wc f32 -> bf16 ----------------
__global__ __launch_bounds__(256)
void k_conv(const float* __restrict__ src, bf16_t* __restrict__ dst){
  size_t i = ((size_t)blockIdx.x * 256 + threadIdx.x) * 4;
  float4 v = *(const float4*)(src + i);
  bf16x4 o = { f2bf(v.x), f2bf(v.y), f2bf(v.z), f2bf(v.w) };
  *(bf16x4*)(dst + i) = o;
}

// ---------------- qp = query @ Wq^T + bq  (f32, 32x32 tiles) ----------------
__global__ __launch_bounds__(256)
void k_qp(const float* __restrict__ query, const float* __restrict__ Wq,
          const float* __restrict__ bq, float* __restrict__ qp){
  __shared__ float qs[32][36];
  __shared__ float wsm[32][36];
  const u32 t  = threadIdx.x;
  const u32 e0 = blockIdx.x * 32, b0 = blockIdx.y * 32;
  const u32 r  = t >> 3, ci = (t & 7) * 4;
  const u32 tm = (t >> 4) * 2, tn = (t & 15) * 2;
  float c00 = 0.f, c01 = 0.f, c10 = 0.f, c11 = 0.f;
  for (u32 k0 = 0; k0 < QD; k0 += 32){
    float4 qv = *(const float4*)(query + (size_t)(b0 + r) * QD + k0 + ci);
    float4 wv = *(const float4*)(Wq    + (size_t)(e0 + r) * QD + k0 + ci);
    __syncthreads();
    *(float4*)&qs[r][ci]  = qv;
    *(float4*)&wsm[r][ci] = wv;
    __syncthreads();
    #pragma unroll
    for (int kq = 0; kq < 8; kq++){
      float4 a0 = *(const float4*)&qs[tm][kq*4];
      float4 a1 = *(const float4*)&qs[tm+1][kq*4];
      float4 b0v = *(const float4*)&wsm[tn][kq*4];
      float4 b1v = *(const float4*)&wsm[tn+1][kq*4];
      c00 += a0.x*b0v.x + a0.y*b0v.y + a0.z*b0v.z + a0.w*b0v.w;
      c01 += a0.x*b1v.x + a0.y*b1v.y + a0.z*b1v.z + a0.w*b1v.w;
      c10 += a1.x*b0v.x + a1.y*b0v.y + a1.z*b0v.z + a1.w*b0v.w;
      c11 += a1.x*b1v.x + a1.y*b1v.y + a1.z*b1v.z + a1.w*b1v.w;
    }
  }
  float bq0 = bq[e0+tn], bq1 = bq[e0+tn+1];
  qp[(size_t)(b0+tm  )*NE + e0+tn  ] = c00 + bq0;
  qp[(size_t)(b0+tm  )*NE + e0+tn+1] = c01 + bq1;
  qp[(size_t)(b0+tm+1)*NE + e0+tn  ] = c10 + bq0;
  qp[(size_t)(b0+tm+1)*NE + e0+tn+1] = c11 + bq1;
}

#define BM 128
#define BN 128
#define BK 32
#define KSTEPS (CD/BK)   // 64

// ===== main: A = f32 ctx via global_load_lds (cvt in-register), ===========
// ===== B = bf16 wcb via global_load_lds; 2-buffer; fused epilogue =========
// LDS: A bufs @0,16384 (128 rows x 128B f32, 8-slot XOR swz)
//      B bufs @32768,40960 (128 rows x 64B bf16, 4-slot XOR swz)
// epilogue overlay: comb[128][136]bf16 @0; qp0 @35840; qp1 @36352; bc @36864
__global__ __launch_bounds__(256, 3)
void k_mainA(const float* __restrict__ ctx, const bf16_t* __restrict__ wcb,
             const float* __restrict__ qp, const float* __restrict__ bcv,
             const float* __restrict__ Wo, float* __restrict__ attn)
{
  __shared__ char smem[49152] __attribute__((aligned(128)));

  const u32 tid  = threadIdx.x;
  const u32 lane = tid & 63;
  const u32 wave = tid >> 6;
  const u32 wm   = wave >> 1;
  const u32 wn   = wave & 1;

  // XCD swizzle: 8 e-chunks of one m-stripe land on one XCD (grid 3136 = 8*392)
  u32 d  = blockIdx.x;
  u32 x  = d & 7;
  u32 s  = d >> 3;
  u32 ec = s & 7;
  u32 j  = s >> 3;
  u32 ms = j * 8 + x;                 // 0..391
  const u32 m0 = ms * BM;
  const u32 e0 = ec * BN;

  // ---- A staging (f32): issue p covers rows p*32..p*32+31; thread row=tid>>3,
  //      phys 16B-slot = tid&7; source quarter = slot ^ (row&7) (involution)
  const u32 arow = tid >> 3;                       // 0..31
  const u32 aq   = (tid & 7) ^ (arow & 7);         // source quarter (4 f32)
  const float* aS = ctx + (size_t)(m0 + arow) * CD + aq * 4;
  char* aD = smem + tid * 16;                      // + p*4096 + buf*16384

  // ---- B staging (bf16): row = tid>>2, phys slot = tid&3, quarter = slot^((row>>1)&3)
  const u32 brow0 = tid >> 2;
  const u32 brow1 = (tid + 256) >> 2;
  const u32 bkq0  = (tid & 3) ^ ((tid >> 3) & 3);
  const u32 bkq1  = (tid & 3) ^ (((tid + 256) >> 3) & 3);
  const bf16_t* bS0 = wcb + (size_t)(e0 + brow0) * CD + bkq0 * 8;
  const bf16_t* bS1 = wcb + (size_t)(e0 + brow1) * CD + bkq1 * 8;
  char* bD0 = smem + 32768 + tid * 16;
  char* bD1 = bD0 + 4096;

  f32x4 acc[4][4];
  #pragma unroll
  for (int i = 0; i < 4; i++)
    #pragma unroll
    for (int jn = 0; jn < 4; jn++) acc[i][jn] = (f32x4){0.f,0.f,0.f,0.f};

  auto stage = [&](u32 buf, u32 ks){
    const u32 ko = ks * BK;            // elements
    // A: 4 issues of 32 rows each (f32)
    #pragma unroll
    for (int p = 0; p < 4; p++)
      load_lds16(aS + (size_t)(p * 32) * CD + ko, aD + buf * 16384u + p * 4096u);
    // B: 2 issues (bf16)
    load_lds16(bS0 + ko, bD0 + buf * 8192u);
    load_lds16(bS1 + ko, bD1 + buf * 8192u);
  };

  const u32 q   = lane >> 4;
  const u32 r15 = lane & 15;
  // A read swizzle: slots (2q)^(r15&7), (2q+1)^(r15&7) of a 128B row
  const u32 as0 = ((2*q)     ^ (r15 & 7)) * 16;
  const u32 as1 = ((2*q + 1) ^ (r15 & 7)) * 16;
  // B read swizzle: slot q^((r15>>1)&3) of a 64B row
  const u32 bsw = (q ^ ((r15 >> 1) & 3)) * 16;

  auto compute = [&](u32 buf){
    const char* A = smem + buf * 16384u;
    const char* B = smem + 32768u + buf * 8192u;
    bf16x8 af[4], bfr[4];
    #pragma unroll
    for (int mt = 0; mt < 4; mt++){
      u32 row = wm*64 + mt*16 + r15;
      const char* rb = A + row * 128u;
      f32x4 lo = *(const f32x4*)(rb + as0);
      f32x4 hi = *(const f32x4*)(rb + as1);
      bf16x8 v = { (bf16_t)lo[0], (bf16_t)lo[1], (bf16_t)lo[2], (bf16_t)lo[3],
                   (bf16_t)hi[0], (bf16_t)hi[1], (bf16_t)hi[2], (bf16_t)hi[3] };
      af[mt] = v;
    }
    #pragma unroll
    for (int nt = 0; nt < 4; nt++){
      u32 row = wn*64 + nt*16 + r15;
      bfr[nt] = *(const bf16x8*)(B + row*64 + bsw);
    }
    #pragma unroll
    for (int mt = 0; mt < 4; mt++)
      #pragma unroll
      for (int nt = 0; nt < 4; nt++)
        acc[mt][nt] = __builtin_amdgcn_mfma_f32_16x16x32_bf16(af[mt], bfr[nt], acc[mt][nt], 0, 0, 0);
  };

  stage(0, 0);
  __syncthreads();
  for (u32 ks = 0; ks < KSTEPS; ks++){
    if (ks + 1 < KSTEPS) stage((ks + 1) & 1, ks + 1);
    compute(ks & 1);
    __syncthreads();
  }

  // ---------------- epilogue ----------------
  float*  qp0  = (float*)(smem + 35840);
  float*  qp1  = (float*)(smem + 36352);
  float*  bcs  = (float*)(smem + 36864);
  bf16_t* comb = (bf16_t*)smem;                // [128][136]

  const u32 b0  = m0 / 196u;
  const u32 bnd = (b0 + 1) * 196u - m0;        // local rows >= bnd belong to b0+1

  if (tid < 128){
    qp0[tid] = qp[(size_t)b0 * NE + e0 + tid];
    bcs[tid] = bcv[e0 + tid];
  } else {
    u32 b1 = b0 + 1; if (b1 >= NB) b1 = NB - 1;
    qp1[tid - 128] = qp[(size_t)b1 * NE + e0 + (tid - 128)];
  }

  // Wo fragments (A operand of attn MFMA): row=g (lane&15), k=e
  bf16x8 wf[4];
  {
    u32 g = lane & 15;
    #pragma unroll
    for (int kk = 0; kk < 4; kk++){
      #pragma unroll
      for (int rr = 0; rr < 8; rr++){
        u32 ei = e0 + kk*32 + q*8 + rr;
        float v = (g < NG) ? Wo[(size_t)g * NE + ei] : 0.0f;
        wf[kk][rr] = f2bf(v);
      }
    }
  }
  __syncthreads();

  // tanh(cp + qp + bc) -> comb (bf16)
  #pragma unroll
  for (int nt = 0; nt < 4; nt++){
    u32 el = wn*64 + nt*16 + r15;
    float qa = qp0[el];
    float qb = qp1[el];
    float bcx = bcs[el];
    #pragma unroll
    for (int mt = 0; mt < 4; mt++){
      u32 rl = wm*64 + mt*16 + q*4;
      #pragma unroll
      for (int r = 0; r < 4; r++){
        u32 row = rl + r;
        float qv = (row >= bnd) ? qb : qa;
        float t = fast_tanh(acc[mt][nt][r] + qv + bcx);
        comb[row*136 + el] = f2bf(t);
      }
    }
  }
  __syncthreads();

  // attn_partial^T[g][n] = sum_e Wo[g,e]*comb[n,e] (two 16-row tiles per wave)
  #pragma unroll
  for (int i = 0; i < 2; i++){
    u32 nrow = (wave*2 + i)*16 + r15;
    f32x4 at = (f32x4){0.f,0.f,0.f,0.f};
    #pragma unroll
    for (int kk = 0; kk < 4; kk++){
      bf16x8 cf = *(const bf16x8*)&comb[nrow*136 + kk*32 + q*8];
      at = __builtin_amdgcn_mfma_f32_16x16x32_bf16(wf[kk], cf, at, 0, 0, 0);
    }
    if (q < 2){
      u32 mrow = m0 + nrow;
      u32 bb = mrow / 196u;
      u32 nn = mrow - bb * 196u;
      #pragma unroll
      for (int r = 0; r < 4; r++){
        u32 g = q*4 + r;
        atomicAdd(&attn[((size_t)bb * NG + g) * NN + nn], at[r]);
      }
    }
  }
}

// ---------------- softmax over n per (b,g) ----------------
__global__ __launch_bounds__(256)
void k_softmax(float* __restrict__ attn){
  u32 flat = blockIdx.x * 4 + (threadIdx.x >> 6);
  u32 lane = threadIdx.x & 63;
  float* row = attn + (size_t)flat * NN;
  float v0 = row[lane];
  float v1 = row[lane + 64];
  float v2 = row[lane + 128];
  float v3 = (lane < 4) ? row[lane + 192] : -1e30f;
  float m = fmaxf(fmaxf(v0, v1), fmaxf(v2, v3));
  #pragma unroll
  for (int o = 1; o < 64; o <<= 1) m = fmaxf(m, __shfl_xor(m, o));
  float e0 = __expf(v0 - m), e1 = __expf(v1 - m), e2 = __expf(v2 - m);
  float e3 = (lane < 4) ? __expf(v3 - m) : 0.f;
  float sum = e0 + e1 + e2 + e3;
  #pragma unroll
  for (int o = 1; o < 64; o <<= 1) sum += __shfl_xor(sum, o);
  float inv = 1.0f / sum;
  row[lane]       = e0 * inv;
  row[lane + 64]  = e1 * inv;
  row[lane + 128] = e2 * inv;
  if (lane < 4) row[lane + 192] = e3 * inv;
}

// -------- glimpse (f32 ctx — accuracy-critical; R4-proven config) --------
__global__ __launch_bounds__(256)
void k_glimpse(const float* __restrict__ ctx, const float* __restrict__ w,
               float* __restrict__ out){
  const u32 b  = blockIdx.y;
  const u32 c0 = blockIdx.x * 512 + threadIdx.x * 2;
  __shared__ float ws_[NG * NN];
  for (u32 i = threadIdx.x; i < NG * NN; i += 256)
    ws_[i] = w[(size_t)b * NG * NN + i];
  __syncthreads();
  const float* cp = ctx + (size_t)b * NN * CD + c0;
  float2 acc[NG];
  #pragma unroll
  for (int g = 0; g < NG; g++) acc[g] = make_float2(0.f, 0.f);
  for (u32 n = 0; n < NN; n++){
    float2 v = *(const float2*)(cp + (size_t)n * CD);
    #pragma unroll
    for (int g = 0; g < NG; g++){
      float wv = ws_[g * NN + n];
      acc[g].x = fmaf(wv, v.x, acc[g].x);
      acc[g].y = fmaf(wv, v.y, acc[g].y);
    }
  }
  #pragma unroll
  for (int g = 0; g < NG; g++)
    *(float2*)(out + (size_t)b * (NG * CD) + (size_t)g * CD + c0) = acc[g];
}

extern "C" void kernel_launch(void* const* d_in, const int* in_sizes, int n_in,
                              void* d_out, int out_size, void* d_ws, size_t ws_size,
                              hipStream_t stream)
{
  const float* ctx   = (const float*)d_in[0];
  const float* query = (const float*)d_in[1];
  const float* Wq    = (const float*)d_in[2];
  const float* bq    = (const float*)d_in[3];
  const float* Wc    = (const float*)d_in[4];
  const float* bc    = (const float*)d_in[5];
  const float* Wo    = (const float*)d_in[6];
  // d_in[7] = bo: constant over softmax axis -> cancels, unused.

  char* ws = (char*)d_ws;
  float*  qp   = (float*)(ws + WS_QP);
  float*  attn = (float*)(ws + WS_ATTN);
  bf16_t* wcb  = (bf16_t*)(ws + WS_WCB);
  float*  out  = (float*)d_out;

  (void)hipMemsetAsync(attn, 0, (size_t)NB * NG * NN * 4, stream);
  k_conv<<<2048, 256, 0, stream>>>(Wc, wcb);
  k_qp<<<dim3(32, 8), 256, 0, stream>>>(query, Wq, bq, qp);
  k_mainA<<<3136, 256, 0, stream>>>(ctx, wcb, qp, bc, Wo, attn);
  k_softmax<<<512, 256, 0, stream>>>(attn);
  k_glimpse<<<dim3(4, 256), 256, 0, stream>>>(ctx, attn, out);
}

// Round 18
// 478.743 us; speedup vs baseline: 1.9741x; 1.0043x over previous
//
#include <hip/hip_runtime.h>
#include <stdint.h>

typedef unsigned int u32;
typedef __bf16 bf16_t;
typedef bf16_t bf16x8 __attribute__((ext_vector_type(8)));
typedef bf16_t bf16x4 __attribute__((ext_vector_type(4)));
typedef float  f32x4  __attribute__((ext_vector_type(4)));

#define NB   256
#define NN   196
#define CD   2048
#define QD   1024
#define NE   1024
#define NG   8

// workspace layout (bytes) — no ctxb: total need ~6.8 MB
#define WS_QP    0
#define WS_ATTN  (NB*NE*4)                              // 1,048,576
#define WS_WCB   (WS_ATTN + NB*NG*NN*4)                 // 2,654,208

__device__ __forceinline__ bf16_t f2bf(float f){
  u32 u = __float_as_uint(f);
  u += 0x7fffu + ((u >> 16) & 1u);            // RNE
  unsigned short h = (unsigned short)(u >> 16);
  return __builtin_bit_cast(bf16_t, h);
}

__device__ __forceinline__ float fast_tanh(float x){
  float e = __expf(2.0f * x);
  return 1.0f - 2.0f / (e + 1.0f);
}

__device__ __forceinline__ void load_lds16(const void* g, void* l){
  __builtin_amdgcn_global_load_lds(
      (const __attribute__((address_space(1))) void*)g,
      (__attribute__((address_space(3))) void*)l, 16, 0, 0);
}

// ---------------- Wc f32 -> bf16 ----------------
__global__ __launch_bounds__(256)
void k_conv(const float* __restrict__ src, bf16_t* __restrict__ dst){
  size_t i = ((size_t)blockIdx.x * 256 + threadIdx.x) * 4;
  float4 v = *(const float4*)(src + i);
  bf16x4 o = { f2bf(v.x), f2bf(v.y), f2bf(v.z), f2bf(v.w) };
  *(bf16x4*)(dst + i) = o;
}

// ---------------- qp = query @ Wq^T + bq  (f32, 32x32 tiles) ----------------
__global__ __launch_bounds__(256)
void k_qp(const float* __restrict__ query, const float* __restrict__ Wq,
          const float* __restrict__ bq, float* __restrict__ qp){
  __shared__ float qs[32][36];
  __shared__ float wsm[32][36];
  const u32 t  = threadIdx.x;
  const u32 e0 = blockIdx.x * 32, b0 = blockIdx.y * 32;
  const u32 r  = t >> 3, ci = (t & 7) * 4;
  const u32 tm = (t >> 4) * 2, tn = (t & 15) * 2;
  float c00 = 0.f, c01 = 0.f, c10 = 0.f, c11 = 0.f;
  for (u32 k0 = 0; k0 < QD; k0 += 32){
    float4 qv = *(const float4*)(query + (size_t)(b0 + r) * QD + k0 + ci);
    float4 wv = *(const float4*)(Wq    + (size_t)(e0 + r) * QD + k0 + ci);
    __syncthreads();
    *(float4*)&qs[r][ci]  = qv;
    *(float4*)&wsm[r][ci] = wv;
    __syncthreads();
    #pragma unroll
    for (int kq = 0; kq < 8; kq++){
      float4 a0 = *(const float4*)&qs[tm][kq*4];
      float4 a1 = *(const float4*)&qs[tm+1][kq*4];
      float4 b0v = *(const float4*)&wsm[tn][kq*4];
      float4 b1v = *(const float4*)&wsm[tn+1][kq*4];
      c00 += a0.x*b0v.x + a0.y*b0v.y + a0.z*b0v.z + a0.w*b0v.w;
      c01 += a0.x*b1v.x + a0.y*b1v.y + a0.z*b1v.z + a0.w*b1v.w;
      c10 += a1.x*b0v.x + a1.y*b0v.y + a1.z*b0v.z + a1.w*b0v.w;
      c11 += a1.x*b1v.x + a1.y*b1v.y + a1.z*b1v.z + a1.w*b1v.w;
    }
  }
  float bq0 = bq[e0+tn], bq1 = bq[e0+tn+1];
  qp[(size_t)(b0+tm  )*NE + e0+tn  ] = c00 + bq0;
  qp[(size_t)(b0+tm  )*NE + e0+tn+1] = c01 + bq1;
  qp[(size_t)(b0+tm+1)*NE + e0+tn  ] = c10 + bq0;
  qp[(size_t)(b0+tm+1)*NE + e0+tn+1] = c11 + bq1;
}

#define BM 128
#define BN 128
#define BK 32
#define KSTEPS (CD/BK)   // 64

// ===== main: A = f32 ctx via global_load_lds (cvt in-register), ===========
// ===== B = bf16 wcb via global_load_lds; 2-buffer; fused epilogue =========
// LDS: A bufs @0,16384 (128 rows x 128B f32, 8-slot XOR swz)
//      B bufs @32768,40960 (128 rows x 64B bf16, 4-slot XOR swz)
// epilogue overlay: comb[128][136]bf16 @0; qp0 @35840; qp1 @36352; bc @36864
__global__ __launch_bounds__(256, 3)
void k_mainA(const float* __restrict__ ctx, const bf16_t* __restrict__ wcb,
             const float* __restrict__ qp, const float* __restrict__ bcv,
             const float* __restrict__ Wo, float* __restrict__ attn)
{
  __shared__ char smem[49152] __attribute__((aligned(128)));

  const u32 tid  = threadIdx.x;
  const u32 lane = tid & 63;
  const u32 wave = tid >> 6;
  const u32 wm   = wave >> 1;
  const u32 wn   = wave & 1;

  // XCD swizzle: 8 e-chunks of one m-stripe land on one XCD (grid 3136 = 8*392)
  u32 d  = blockIdx.x;
  u32 x  = d & 7;
  u32 s  = d >> 3;
  u32 ec = s & 7;
  u32 j  = s >> 3;
  u32 ms = j * 8 + x;                 // 0..391
  const u32 m0 = ms * BM;
  const u32 e0 = ec * BN;

  // ---- A staging (f32): issue p covers rows p*32..p*32+31; thread row=tid>>3,
  //      phys 16B-slot = tid&7; source quarter = slot ^ (row&7) (involution)
  const u32 arow = tid >> 3;                       // 0..31
  const u32 aq   = (tid & 7) ^ (arow & 7);         // source quarter (4 f32)
  const float* aS = ctx + (size_t)(m0 + arow) * CD + aq * 4;
  char* aD = smem + tid * 16;                      // + p*4096 + buf*16384

  // ---- B staging (bf16): row = tid>>2, phys slot = tid&3, quarter = slot^((row>>1)&3)
  const u32 brow0 = tid >> 2;
  const u32 brow1 = (tid + 256) >> 2;
  const u32 bkq0  = (tid & 3) ^ ((tid >> 3) & 3);
  const u32 bkq1  = (tid & 3) ^ (((tid + 256) >> 3) & 3);
  const bf16_t* bS0 = wcb + (size_t)(e0 + brow0) * CD + bkq0 * 8;
  const bf16_t* bS1 = wcb + (size_t)(e0 + brow1) * CD + bkq1 * 8;
  char* bD0 = smem + 32768 + tid * 16;
  char* bD1 = bD0 + 4096;

  f32x4 acc[4][4];
  #pragma unroll
  for (int i = 0; i < 4; i++)
    #pragma unroll
    for (int jn = 0; jn < 4; jn++) acc[i][jn] = (f32x4){0.f,0.f,0.f,0.f};

  auto stage = [&](u32 buf, u32 ks){
    const u32 ko = ks * BK;            // elements
    // A: 4 issues of 32 rows each (f32)
    #pragma unroll
    for (int p = 0; p < 4; p++)
      load_lds16(aS + (size_t)(p * 32) * CD + ko, aD + buf * 16384u + p * 4096u);
    // B: 2 issues (bf16)
    load_lds16(bS0 + ko, bD0 + buf * 8192u);
    load_lds16(bS1 + ko, bD1 + buf * 8192u);
  };

  const u32 q   = lane >> 4;
  const u32 r15 = lane & 15;
  // A read swizzle: slots (2q)^(r15&7), (2q+1)^(r15&7) of a 128B row
  const u32 as0 = ((2*q)     ^ (r15 & 7)) * 16;
  const u32 as1 = ((2*q + 1) ^ (r15 & 7)) * 16;
  // B read swizzle: slot q^((r15>>1)&3) of a 64B row
  const u32 bsw = (q ^ ((r15 >> 1) & 3)) * 16;

  auto compute = [&](u32 buf){
    const char* A = smem + buf * 16384u;
    const char* B = smem + 32768u + buf * 8192u;
    bf16x8 af[4], bfr[4];
    #pragma unroll
    for (int mt = 0; mt < 4; mt++){
      u32 row = wm*64 + mt*16 + r15;
      const char* rb = A + row * 128u;
      f32x4 lo = *(const f32x4*)(rb + as0);
      f32x4 hi = *(const f32x4*)(rb + as1);
      bf16x8 v = { (bf16_t)lo[0], (bf16_t)lo[1], (bf16_t)lo[2], (bf16_t)lo[3],
                   (bf16_t)hi[0], (bf16_t)hi[1], (bf16_t)hi[2], (bf16_t)hi[3] };
      af[mt] = v;
    }
    #pragma unroll
    for (int nt = 0; nt < 4; nt++){
      u32 row = wn*64 + nt*16 + r15;
      bfr[nt] = *(const bf16x8*)(B + row*64 + bsw);
    }
    #pragma unroll
    for (int mt = 0; mt < 4; mt++)
      #pragma unroll
      for (int nt = 0; nt < 4; nt++)
        acc[mt][nt] = __builtin_amdgcn_mfma_f32_16x16x32_bf16(af[mt], bfr[nt], acc[mt][nt], 0, 0, 0);
  };

  stage(0, 0);
  __syncthreads();
  for (u32 ks = 0; ks < KSTEPS; ks++){
    if (ks + 1 < KSTEPS) stage((ks + 1) & 1, ks + 1);
    compute(ks & 1);
    __syncthreads();
  }

  // ---------------- epilogue ----------------
  float*  qp0  = (float*)(smem + 35840);
  float*  qp1  = (float*)(smem + 36352);
  float*  bcs  = (float*)(smem + 36864);
  bf16_t* comb = (bf16_t*)smem;                // [128][136]

  const u32 b0  = m0 / 196u;
  const u32 bnd = (b0 + 1) * 196u - m0;        // local rows >= bnd belong to b0+1

  if (tid < 128){
    qp0[tid] = qp[(size_t)b0 * NE + e0 + tid];
    bcs[tid] = bcv[e0 + tid];
  } else {
    u32 b1 = b0 + 1; if (b1 >= NB) b1 = NB - 1;
    qp1[tid - 128] = qp[(size_t)b1 * NE + e0 + (tid - 128)];
  }

  // Wo fragments (A operand of attn MFMA): row=g (lane&15), k=e
  bf16x8 wf[4];
  {
    u32 g = lane & 15;
    #pragma unroll
    for (int kk = 0; kk < 4; kk++){
      #pragma unroll
      for (int rr = 0; rr < 8; rr++){
        u32 ei = e0 + kk*32 + q*8 + rr;
        float v = (g < NG) ? Wo[(size_t)g * NE + ei] : 0.0f;
        wf[kk][rr] = f2bf(v);
      }
    }
  }
  __syncthreads();

  // tanh(cp + qp + bc) -> comb (bf16)
  #pragma unroll
  for (int nt = 0; nt < 4; nt++){
    u32 el = wn*64 + nt*16 + r15;
    float qa = qp0[el];
    float qb = qp1[el];
    float bcx = bcs[el];
    #pragma unroll
    for (int mt = 0; mt < 4; mt++){
      u32 rl = wm*64 + mt*16 + q*4;
      #pragma unroll
      for (int r = 0; r < 4; r++){
        u32 row = rl + r;
        float qv = (row >= bnd) ? qb : qa;
        float t = fast_tanh(acc[mt][nt][r] + qv + bcx);
        comb[row*136 + el] = f2bf(t);
      }
    }
  }
  __syncthreads();

  // attn_partial^T[g][n] = sum_e Wo[g,e]*comb[n,e] (two 16-row tiles per wave)
  #pragma unroll
  for (int i = 0; i < 2; i++){
    u32 nrow = (wave*2 + i)*16 + r15;
    f32x4 at = (f32x4){0.f,0.f,0.f,0.f};
    #pragma unroll
    for (int kk = 0; kk < 4; kk++){
      bf16x8 cf = *(const bf16x8*)&comb[nrow*136 + kk*32 + q*8];
      at = __builtin_amdgcn_mfma_f32_16x16x32_bf16(wf[kk], cf, at, 0, 0, 0);
    }
    if (q < 2){
      u32 mrow = m0 + nrow;
      u32 bb = mrow / 196u;
      u32 nn = mrow - bb * 196u;
      #pragma unroll
      for (int r = 0; r < 4; r++){
        u32 g = q*4 + r;
        atomicAdd(&attn[((size_t)bb * NG + g) * NN + nn], at[r]);
      }
    }
  }
}

// -------- glimpse with fused softmax (f32 ctx — accuracy-critical) --------
// attn holds RAW logits; each block normalizes its batch's [8][196] in LDS
// (identical per-row arithmetic/order to the old k_softmax), then pools.
__global__ __launch_bounds__(256)
void k_glimpse_sm(const float* __restrict__ ctx, const float* __restrict__ attn,
                  float* __restrict__ out){
  const u32 b  = blockIdx.y;
  const u32 c0 = blockIdx.x * 512 + threadIdx.x * 2;
  __shared__ float ws_[NG * NN];
  const u32 wave = threadIdx.x >> 6;
  const u32 lane = threadIdx.x & 63;

  // softmax: wave w handles rows g = 2w, 2w+1
  #pragma unroll
  for (int i = 0; i < 2; i++){
    u32 g = wave * 2 + i;
    const float* row = attn + ((size_t)b * NG + g) * NN;
    float v0 = row[lane];
    float v1 = row[lane + 64];
    float v2 = row[lane + 128];
    float v3 = (lane < 4) ? row[lane + 192] : -1e30f;
    float m = fmaxf(fmaxf(v0, v1), fmaxf(v2, v3));
    #pragma unroll
    for (int o = 1; o < 64; o <<= 1) m = fmaxf(m, __shfl_xor(m, o));
    float e0 = __expf(v0 - m), e1 = __expf(v1 - m), e2 = __expf(v2 - m);
    float e3 = (lane < 4) ? __expf(v3 - m) : 0.f;
    float sum = e0 + e1 + e2 + e3;
    #pragma unroll
    for (int o = 1; o < 64; o <<= 1) sum += __shfl_xor(sum, o);
    float inv = 1.0f / sum;
    ws_[g * NN + lane]       = e0 * inv;
    ws_[g * NN + lane + 64]  = e1 * inv;
    ws_[g * NN + lane + 128] = e2 * inv;
    if (lane < 4) ws_[g * NN + lane + 192] = e3 * inv;
  }
  __syncthreads();

  const float* cp = ctx + (size_t)b * NN * CD + c0;
  float2 acc[NG];
  #pragma unroll
  for (int g = 0; g < NG; g++) acc[g] = make_float2(0.f, 0.f);
  for (u32 n = 0; n < NN; n++){
    float2 v = *(const float2*)(cp + (size_t)n * CD);
    #pragma unroll
    for (int g = 0; g < NG; g++){
      float wv = ws_[g * NN + n];
      acc[g].x = fmaf(wv, v.x, acc[g].x);
      acc[g].y = fmaf(wv, v.y, acc[g].y);
    }
  }
  #pragma unroll
  for (int g = 0; g < NG; g++)
    *(float2*)(out + (size_t)b * (NG * CD) + (size_t)g * CD + c0) = acc[g];
}

extern "C" void kernel_launch(void* const* d_in, const int* in_sizes, int n_in,
                              void* d_out, int out_size, void* d_ws, size_t ws_size,
                              hipStream_t stream)
{
  const float* ctx   = (const float*)d_in[0];
  const float* query = (const float*)d_in[1];
  const float* Wq    = (const float*)d_in[2];
  const float* bq    = (const float*)d_in[3];
  const float* Wc    = (const float*)d_in[4];
  const float* bc    = (const float*)d_in[5];
  const float* Wo    = (const float*)d_in[6];
  // d_in[7] = bo: constant over softmax axis -> cancels, unused.

  char* ws = (char*)d_ws;
  float*  qp   = (float*)(ws + WS_QP);
  float*  attn = (float*)(ws + WS_ATTN);
  bf16_t* wcb  = (bf16_t*)(ws + WS_WCB);
  float*  out  = (float*)d_out;

  (void)hipMemsetAsync(attn, 0, (size_t)NB * NG * NN * 4, stream);
  k_conv<<<2048, 256, 0, stream>>>(Wc, wcb);
  k_qp<<<dim3(32, 8), 256, 0, stream>>>(query, Wq, bq, qp);
  k_mainA<<<3136, 256, 0, stream>>>(ctx, wcb, qp, bc, Wo, attn);
  k_glimpse_sm<<<dim3(4, 256), 256, 0, stream>>>(ctx, attn, out);
}